// Round 7
// baseline (12842.693 us; speedup 1.0000x reference)
//
#include <hip/hip_runtime.h>

// 2-layer LSTM (B=32, T=512, D=H=1024), persistent dataflow kernel, MI355X.
// Round 7: blocks 0..127 = layer 0, 128..255 = layer 1 (chases via dataflow).
// Block owns 8 h-cols -> 32 gate rows {f,i,o,cg}x8.
//  - Weights held in REGISTERS (32 bf16x8 frags/wave = 128 VGPR), loaded once.
//    No LDS weight staging at all.
//  - Sync: per-producer monotonic flag fl[lb]=t+1 (plain sc0 sc1 store after
//    vmcnt(0) data ack; single writer, no atomics). Consumers poll all 128
//    flags via ONE coalesced dwordx2 sc0 sc1 wave-load.
//  - h layout [t][lb][b][8] bf16: producer publish = 512B contiguous;
//    consumer 16B chunks = (k>>3)*512 + b*16.
//  - h0/h1 both full-T write-once buffers -> plain cached consumer loads are
//    stale-proof (each address written once/dispatch, read only after flag).
//  - B loads pipelined with MFMA via counted vmcnt(24/16/8/0)+sched_barrier.
// 4 waves = {input part, recurrent part} x {K-chunk 0,1}; ~330 VGPR -> 1
// wave/SIMD -> 1 block/CU -> all 256 blocks co-resident (deadlock-free).

#define BB 32
#define TT 512
#define HH 1024
#define NBLK 128
#define SLICE 65536   // bytes per h time-slice: [128 lb][32 b][8 j] bf16

typedef float f32x4 __attribute__((ext_vector_type(4)));
typedef __bf16 bf16x8 __attribute__((ext_vector_type(8)));
typedef unsigned int u32x4 __attribute__((ext_vector_type(4)));
typedef int i32x2 __attribute__((ext_vector_type(2)));

// ws layout (bytes); rounds 0/3/5/6 proved ws_size >= ~67.25MB
#define H0_OFF 0
#define H1_OFF ((size_t)TT * SLICE)        // 33,554,432
#define FL_OFF ((size_t)2 * TT * SLICE)    // 67,108,864: fl0[128] | fl1[128]

// plain cached 16B load (L2-shared per XCD)
#define LDC16(d, a) asm volatile("global_load_dwordx4 %0, %1, off" \
                                 : "=v"(d) : "v"(a) : "memory")
// write-through coherent 16B store
#define ST16(a, v) asm volatile("global_store_dwordx4 %0, %1, off sc0 sc1" \
                                :: "v"(a), "v"(v) : "memory")
#define WAITV(N) asm volatile("s_waitcnt vmcnt(" #N ")" ::: "memory"); \
                 __builtin_amdgcn_sched_barrier(0)

__device__ __forceinline__ float sigm(float x){ return 1.f/(1.f+__expf(-x)); }
__device__ __forceinline__ float tanh_s(float x){
  float a = fminf(fabsf(x), 20.f);
  float e = __expf(2.f*a);
  float r = (e-1.f)/(e+1.f);
  return x < 0.f ? -r : r;
}
// poll 128 monotonic flags (coalesced dwordx2/lane, coherent) until all >= need
__device__ __forceinline__ void pollge(const int* fl, int lane, int need){
  const int* p = fl + 2*lane;
  for (;;){
    i32x2 v;
    asm volatile("global_load_dwordx2 %0, %1, off sc0 sc1\n\ts_waitcnt vmcnt(0)"
                 : "=v"(v) : "v"(p) : "memory");
    if (!__any((v[0] < need) | (v[1] < need))) return;
    __builtin_amdgcn_s_sleep(1);
  }
}
__device__ __forceinline__ bf16x8 cvt8(float4 a, float4 b){
  bf16x8 r;
  r[0]=(__bf16)a.x; r[1]=(__bf16)a.y; r[2]=(__bf16)a.z; r[3]=(__bf16)a.w;
  r[4]=(__bf16)b.x; r[5]=(__bf16)b.y; r[6]=(__bf16)b.z; r[7]=(__bf16)b.w;
  return r;
}

__global__ __launch_bounds__(256, 1) void lstm2(
    const float* __restrict__ x, const int* __restrict__ l32,
    const float* __restrict__ wih0, const float* __restrict__ whh0, const float* __restrict__ b0,
    const float* __restrict__ wih1, const float* __restrict__ whh1, const float* __restrict__ b1,
    float* __restrict__ out, char* __restrict__ ws)
{
  __shared__ float redf[4*1152];        // [wid][32 col][36]
  __shared__ __bf16 hstage[BB*8];       // [b][j]
  const int tid = threadIdx.x, bid = blockIdx.x;
  const int layer = bid >> 7, lb = bid & (NBLK-1), c0 = lb*8;
  const float* bias = layer ? b1 : b0;
  char* h0 = ws + H0_OFF;
  char* h1 = ws + H1_OFF;
  int* fl0 = (int*)(ws + FL_OFF);
  int* fl1 = fl0 + NBLK;

  // lengths: int32 vs int64 detect (odd words all-zero => int64)
  int odd = 0;
#pragma unroll
  for (int i = 1; i < 32; i += 2) odd |= l32[i];
  const int eb = tid >> 3, ec = tid & 7, cgl = c0 + ec;
  const int mylen = odd ? l32[eb] : l32[2*eb];
  float bias_r[4];
#pragma unroll
  for (int g = 0; g < 4; ++g) bias_r[g] = bias[g*HH + cgl];
  float c_st = 0.f, h_st = 0.f;

  const int lane = tid & 63, wid = tid >> 6;
  const int part = wid >> 1;            // 0: input part (x / h0), 1: recurrent
  const int kch  = wid & 1;             // K-chunk of 512
  const int col16 = lane & 15, kgrp = lane >> 4;
  float* wr = redf + wid*1152;
  const int kbase = kch*512 + kgrp*8;

  // ---- weight fragments -> registers (t-invariant; 32 frags = 128 VGPR) ----
  const float* wsel = part ? (layer ? whh1 : whh0) : (layer ? wih1 : wih0);
  const int m0 = col16, m1 = 16 + col16;
  const float* ws0 = wsel + (size_t)((m0>>3)*HH + c0 + (m0&7))*HH + kbase;
  const float* ws1 = wsel + (size_t)((m1>>3)*HH + c0 + (m1&7))*HH + kbase;
  bf16x8 wa[16], wb[16];
#pragma unroll
  for (int u = 0; u < 16; ++u){
    wa[u] = cvt8(*(const float4*)(ws0 + u*32), *(const float4*)(ws0 + u*32 + 4));
    wb[u] = cvt8(*(const float4*)(ws1 + u*32), *(const float4*)(ws1 + u*32 + 4));
  }

  for (int t = 0; t < TT; ++t){
    f32x4 acc00={0,0,0,0}, acc01={0,0,0,0}, acc10={0,0,0,0}, acc11={0,0,0,0};

    // ---- B source + flag wait ----
    const char* sb = nullptr;
    const float* fsrc = nullptr;
    const int* fl = nullptr; int need = 0;
    if (layer == 0){
      if (part == 0) fsrc = x + (t << 10);
      else if (t > 0){ sb = h0 + (size_t)(t-1)*SLICE; fl = fl0; need = t; }
    } else {
      if (part == 0){ sb = h0 + (size_t)t*SLICE; fl = fl0; need = t+1; }
      else if (t > 0){ sb = h1 + (size_t)(t-1)*SLICE; fl = fl1; need = t; }
    }
    if (fl) pollge(fl, lane, need);

    if (sb){
      // h layout [lb][b][8]: chunk(k0,b) at (k0>>3)*512 + b*16
      const char* bbase = sb + (size_t)(kch*64 + kgrp)*512 + col16*16;
      u32x4 ra[16], rb[16];
#pragma unroll
      for (int u = 0; u < 16; ++u){
        LDC16(ra[u], bbase + u*2048);
        LDC16(rb[u], bbase + u*2048 + 256);
      }
#define MMQ(u) { bf16x8 bv0 = __builtin_bit_cast(bf16x8, ra[u]); \
                 bf16x8 bv1 = __builtin_bit_cast(bf16x8, rb[u]); \
  acc00 = __builtin_amdgcn_mfma_f32_16x16x32_bf16(wa[u], bv0, acc00, 0,0,0); \
  acc01 = __builtin_amdgcn_mfma_f32_16x16x32_bf16(wa[u], bv1, acc01, 0,0,0); \
  acc10 = __builtin_amdgcn_mfma_f32_16x16x32_bf16(wb[u], bv0, acc10, 0,0,0); \
  acc11 = __builtin_amdgcn_mfma_f32_16x16x32_bf16(wb[u], bv1, acc11, 0,0,0); }
      WAITV(24); MMQ(0);  MMQ(1);  MMQ(2);  MMQ(3);
      WAITV(16); MMQ(4);  MMQ(5);  MMQ(6);  MMQ(7);
      WAITV(8);  MMQ(8);  MMQ(9);  MMQ(10); MMQ(11);
      WAITV(0);  MMQ(12); MMQ(13); MMQ(14); MMQ(15);
#undef MMQ
    } else if (fsrc){
      // L0 input part: cached fp32 x[b][t][d] reads, in-register cvt
      const float* p0 = fsrc + ((size_t)col16 << 19) + kbase;
      const float* p1 = fsrc + ((size_t)(16+col16) << 19) + kbase;
#pragma unroll 4
      for (int u = 0; u < 16; ++u){
        bf16x8 bv0 = cvt8(*(const float4*)(p0 + u*32), *(const float4*)(p0 + u*32 + 4));
        bf16x8 bv1 = cvt8(*(const float4*)(p1 + u*32), *(const float4*)(p1 + u*32 + 4));
        acc00 = __builtin_amdgcn_mfma_f32_16x16x32_bf16(wa[u], bv0, acc00, 0,0,0);
        acc01 = __builtin_amdgcn_mfma_f32_16x16x32_bf16(wa[u], bv1, acc01, 0,0,0);
        acc10 = __builtin_amdgcn_mfma_f32_16x16x32_bf16(wb[u], bv0, acc10, 0,0,0);
        acc11 = __builtin_amdgcn_mfma_f32_16x16x32_bf16(wb[u], bv1, acc11, 0,0,0);
      }
    }

    // ---- partials -> LDS, transposed: redf[wid][col][m] ----
    *(f32x4*)(wr + col16*36 + kgrp*4)           = acc00;
    *(f32x4*)(wr + (16+col16)*36 + kgrp*4)      = acc01;
    *(f32x4*)(wr + col16*36 + 16 + kgrp*4)      = acc10;
    *(f32x4*)(wr + (16+col16)*36 + 16 + kgrp*4) = acc11;
    __syncthreads();

    // ---- pointwise LSTM update: thread = (batch eb, col ec) ----
    float vv[4];
#pragma unroll
    for (int g = 0; g < 4; ++g){
      int mi = eb*36 + g*8 + ec;
      vv[g] = redf[mi] + redf[1152+mi] + redf[2304+mi] + redf[3456+mi] + bias_r[g];
    }
    float fg = sigm(vv[0]), ig = sigm(vv[1]), og = sigm(vv[2]), gg = tanh_s(vv[3]);
    float cn = fg*c_st + ig*gg;
    float hn = og*tanh_s(cn);
    if (t < mylen){ c_st = cn; h_st = hn; }   // hold semantics for t >= len
    hstage[tid] = (__bf16)h_st;               // [eb][ec] = tid
    __syncthreads();

    // ---- publish: wave0 writes 512B contiguous through to MALL, then flag ----
    if (wid == 0){
      char* hb = (layer ? h1 : h0) + (size_t)t*SLICE + lb*512;
      if (lane < 32){
        u32x4 hv = *(const u32x4*)(hstage + lane*8);
        ST16(hb + lane*16, hv);
      }
      asm volatile("s_waitcnt vmcnt(0)" ::: "memory");   // data acked at MALL
      if (lane == 0){
        int* fp = (layer ? fl1 : fl0) + lb;
        int val = t + 1;
        asm volatile("global_store_dword %0, %1, off sc0 sc1"
                     :: "v"(fp), "v"(val) : "memory");
      }
    }
    if (layer) out[((size_t)(eb*TT + t) << 10) + cgl] = h_st;  // out1[b][t][h]
  }

  // finals: out1 | c[2][B][H] | h[2][B][H]
  const size_t OFFC = (size_t)BB*TT*HH;
  out[OFFC + (layer << 15) + (eb << 10) + cgl] = c_st;
  out[OFFC + ((2 + layer) << 15) + (eb << 10) + cgl] = h_st;
}

extern "C" void kernel_launch(void* const* d_in, const int* in_sizes, int n_in,
                              void* d_out, int out_size, void* d_ws, size_t ws_size,
                              hipStream_t stream) {
  const float* x    = (const float*)d_in[0];
  const int*   lens = (const int*)d_in[1];
  const float* wih0 = (const float*)d_in[2];
  const float* whh0 = (const float*)d_in[3];
  const float* b0   = (const float*)d_in[4];
  const float* wih1 = (const float*)d_in[5];
  const float* whh1 = (const float*)d_in[6];
  const float* b1   = (const float*)d_in[7];
  float* out = (float*)d_out;
  char* ws = (char*)d_ws;

  // zero the flag words (ws is re-poisoned 0xAA before every timed call)
  (void)hipMemsetAsync(ws + FL_OFF, 0, 1024, stream);

  lstm2<<<dim3(256), dim3(256), 0, stream>>>(
      x, lens, wih0, whh0, b0, wih1, whh1, b1, out, ws);
}

// Round 8
// 4821.411 us; speedup vs baseline: 2.6637x; 2.6637x over previous
//
#include <hip/hip_runtime.h>

// 2-layer LSTM (B=32, T=512, D=H=1024), persistent dataflow kernel, MI355X.
// Round 8 = round 7 with ONE change: weights back in LDS (round-6 proven
// machinery; round 7's weights-in-VGPR spilled -> scratch thrash, 2.5x slower).
// Kept from round 7 (all numerically verified):
//  - per-producer monotonic flag fl[lb]=t+1 (plain sc0 sc1 dword store after
//    vmcnt(0) data ack; single writer, NO atomics). Consumers poll all 128
//    flags with one coalesced dwordx2 sc0 sc1 wave-load.
//  - h layout [t][lb][b][8] bf16 (SLICE=64KB): publish = 512B contiguous;
//    B-loads dense (8 cache lines / instruction vs 64 sparse in round 6).
//  - h0/h1 full-T write-once buffers -> plain cached consumer reads are
//    stale-proof (written once per dispatch, read only after flag).
//  - B-load -> MFMA pipelined via counted vmcnt(24/16/8/0) + sched_barrier.
//  - L0 input part reads x fp32 directly (cached, converts in-register).
// Blocks 0..127 = layer 0, 128..255 = layer 1. Block owns 8 h-cols ->
// 32 gate rows {f,i,o,cg}x8. 4 waves = {input,recurrent} x {K-chunk 0,1}.
// 150KB LDS -> 1 block/CU -> all 256 blocks co-resident (deadlock-free).

#define BB 32
#define TT 512
#define HH 1024
#define NBLK 128
#define SLICE 65536   // bytes per h time-slice: [128 lb][32 b][8 j] bf16

typedef float f32x4 __attribute__((ext_vector_type(4)));
typedef __bf16 bf16x8 __attribute__((ext_vector_type(8)));
typedef unsigned int u32x4 __attribute__((ext_vector_type(4)));
typedef int i32x2 __attribute__((ext_vector_type(2)));

// ws layout (bytes); rounds 0/3/5/6/7 proved ws_size >= ~67.1MB
#define H0_OFF 0
#define H1_OFF ((size_t)TT * SLICE)        // 33,554,432
#define FL_OFF ((size_t)2 * TT * SLICE)    // 67,108,864: fl0[128] | fl1[128]

// plain cached 16B load (L2-shared per XCD)
#define LDC16(d, a) asm volatile("global_load_dwordx4 %0, %1, off" \
                                 : "=v"(d) : "v"(a) : "memory")
// write-through coherent 16B store
#define ST16(a, v) asm volatile("global_store_dwordx4 %0, %1, off sc0 sc1" \
                                :: "v"(a), "v"(v) : "memory")
#define WAITV(N) asm volatile("s_waitcnt vmcnt(" #N ")" ::: "memory"); \
                 __builtin_amdgcn_sched_barrier(0)

__device__ __forceinline__ float sigm(float x){ return 1.f/(1.f+__expf(-x)); }
__device__ __forceinline__ float tanh_s(float x){
  float a = fminf(fabsf(x), 20.f);
  float e = __expf(2.f*a);
  float r = (e-1.f)/(e+1.f);
  return x < 0.f ? -r : r;
}
// poll 128 monotonic flags (coalesced dwordx2/lane, coherent) until all >= need
__device__ __forceinline__ void pollge(const int* fl, int lane, int need){
  const int* p = fl + 2*lane;
  for (;;){
    i32x2 v;
    asm volatile("global_load_dwordx2 %0, %1, off sc0 sc1\n\ts_waitcnt vmcnt(0)"
                 : "=v"(v) : "v"(p) : "memory");
    if (!__any((v[0] < need) | (v[1] < need))) return;
    __builtin_amdgcn_s_sleep(1);
  }
}
__device__ __forceinline__ bf16x8 cvt8(float4 a, float4 b){
  bf16x8 r;
  r[0]=(__bf16)a.x; r[1]=(__bf16)a.y; r[2]=(__bf16)a.z; r[3]=(__bf16)a.w;
  r[4]=(__bf16)b.x; r[5]=(__bf16)b.y; r[6]=(__bf16)b.z; r[7]=(__bf16)b.w;
  return r;
}

__global__ __launch_bounds__(256, 1) void lstm2(
    const float* __restrict__ x, const int* __restrict__ l32,
    const float* __restrict__ wih0, const float* __restrict__ whh0, const float* __restrict__ b0,
    const float* __restrict__ wih1, const float* __restrict__ whh1, const float* __restrict__ b1,
    float* __restrict__ out, char* __restrict__ ws)
{
  extern __shared__ char smem[];
  // [0,64K): wih rows bf16 swizzled; [64K,128K): whh; then redf + hstage
  float* redf = (float*)(smem + 131072);        // [4][32][36] f32
  __bf16* hstage = (__bf16*)(smem + 131072 + 18432);  // [32 b][8 j]
  const int tid = threadIdx.x, bid = blockIdx.x;
  const int layer = bid >> 7, lb = bid & (NBLK-1), c0 = lb*8;
  const float* wih  = layer ? wih1 : wih0;
  const float* whh  = layer ? whh1 : whh0;
  const float* bias = layer ? b1 : b0;
  char* h0 = ws + H0_OFF;
  char* h1 = ws + H1_OFF;
  int* fl0 = (int*)(ws + FL_OFF);
  int* fl1 = fl0 + NBLK;

  // ---- weights -> LDS bf16, XOR-swizzle byte ^= (m&15)<<4 (round-6 proven) ----
  for (int idx = tid; idx < 32*1024; idx += 256){
    int m = idx >> 10, k = idx & (HH-1);
    int gr = (m >> 3)*HH + c0 + (m & 7);        // gates {f,i,o,cg} x 8 cols
    int off = m*2048 + ((k*2) ^ ((m & 15) << 4));
    *(__bf16*)(smem + off)         = (__bf16)wih[(size_t)gr*HH + k];
    *(__bf16*)(smem + 65536 + off) = (__bf16)whh[(size_t)gr*HH + k];
  }

  // lengths: int32 vs int64 detect (odd words all-zero => int64)
  int odd = 0;
#pragma unroll
  for (int i = 1; i < 32; i += 2) odd |= l32[i];
  const int eb = tid >> 3, ec = tid & 7, cgl = c0 + ec;
  const int mylen = odd ? l32[eb] : l32[2*eb];
  float bias_r[4];
#pragma unroll
  for (int g = 0; g < 4; ++g) bias_r[g] = bias[g*HH + cgl];
  float c_st = 0.f, h_st = 0.f;

  const int lane = tid & 63, wid = tid >> 6;
  const int part = wid >> 1;            // 0: input part (x / h0), 1: recurrent
  const int kch  = wid & 1;             // K-chunk of 512
  const int col16 = lane & 15, kgrp = lane >> 4;
  const int axor = col16 << 4;
  const char* wbase = (const char*)smem + part*65536 + col16*2048 + kch*1024;
  float* wr = redf + wid*1152;
  const int kbase = kch*512 + kgrp*8;

  __syncthreads();                      // weights visible

  for (int t = 0; t < TT; ++t){
    f32x4 acc00={0,0,0,0}, acc01={0,0,0,0}, acc10={0,0,0,0}, acc11={0,0,0,0};

    // ---- B source + flag wait ----
    const char* sb = nullptr;
    const float* fsrc = nullptr;
    const int* fl = nullptr; int need = 0;
    if (layer == 0){
      if (part == 0) fsrc = x + (t << 10);
      else if (t > 0){ sb = h0 + (size_t)(t-1)*SLICE; fl = fl0; need = t; }
    } else {
      if (part == 0){ sb = h0 + (size_t)t*SLICE; fl = fl0; need = t+1; }
      else if (t > 0){ sb = h1 + (size_t)(t-1)*SLICE; fl = fl1; need = t; }
    }
    if (fl) pollge(fl, lane, need);

    if (sb){
      // SLICE layout [lb][b][8]: chunk(k-octet jo, b) at jo*512 + b*16
      const char* bbase = sb + (size_t)(kch*64 + kgrp)*512 + col16*16;
      u32x4 ra[16], rb[16];
#pragma unroll
      for (int u = 0; u < 16; ++u){
        LDC16(ra[u], bbase + u*2048);           // batches 0..15
        LDC16(rb[u], bbase + u*2048 + 256);     // batches 16..31
      }
#define MMQ(u) { bf16x8 bv0 = __builtin_bit_cast(bf16x8, ra[u]); \
                 bf16x8 bv1 = __builtin_bit_cast(bf16x8, rb[u]); \
                 int ao = ((u)*64 + kgrp*16) ^ axor; \
                 bf16x8 a0 = *(const bf16x8*)(wbase + ao); \
                 bf16x8 a1 = *(const bf16x8*)(wbase + 32768 + ao); \
  acc00 = __builtin_amdgcn_mfma_f32_16x16x32_bf16(a0, bv0, acc00, 0,0,0); \
  acc01 = __builtin_amdgcn_mfma_f32_16x16x32_bf16(a0, bv1, acc01, 0,0,0); \
  acc10 = __builtin_amdgcn_mfma_f32_16x16x32_bf16(a1, bv0, acc10, 0,0,0); \
  acc11 = __builtin_amdgcn_mfma_f32_16x16x32_bf16(a1, bv1, acc11, 0,0,0); }
      WAITV(24); MMQ(0);  MMQ(1);  MMQ(2);  MMQ(3);
      WAITV(16); MMQ(4);  MMQ(5);  MMQ(6);  MMQ(7);
      WAITV(8);  MMQ(8);  MMQ(9);  MMQ(10); MMQ(11);
      WAITV(0);  MMQ(12); MMQ(13); MMQ(14); MMQ(15);
#undef MMQ
    } else if (fsrc){
      // L0 input part: cached fp32 x[b][t][d] reads, in-register cvt
      const float* p0 = fsrc + ((size_t)col16 << 19) + kbase;
      const float* p1 = fsrc + ((size_t)(16+col16) << 19) + kbase;
#pragma unroll 4
      for (int u = 0; u < 16; ++u){
        bf16x8 bv0 = cvt8(*(const float4*)(p0 + u*32), *(const float4*)(p0 + u*32 + 4));
        bf16x8 bv1 = cvt8(*(const float4*)(p1 + u*32), *(const float4*)(p1 + u*32 + 4));
        int ao = (u*64 + kgrp*16) ^ axor;
        bf16x8 a0 = *(const bf16x8*)(wbase + ao);
        bf16x8 a1 = *(const bf16x8*)(wbase + 32768 + ao);
        acc00 = __builtin_amdgcn_mfma_f32_16x16x32_bf16(a0, bv0, acc00, 0,0,0);
        acc01 = __builtin_amdgcn_mfma_f32_16x16x32_bf16(a0, bv1, acc01, 0,0,0);
        acc10 = __builtin_amdgcn_mfma_f32_16x16x32_bf16(a1, bv0, acc10, 0,0,0);
        acc11 = __builtin_amdgcn_mfma_f32_16x16x32_bf16(a1, bv1, acc11, 0,0,0);
      }
    }

    // ---- partials -> LDS, transposed: redf[wid][col][m] ----
    *(f32x4*)(wr + col16*36 + kgrp*4)           = acc00;
    *(f32x4*)(wr + (16+col16)*36 + kgrp*4)      = acc01;
    *(f32x4*)(wr + col16*36 + 16 + kgrp*4)      = acc10;
    *(f32x4*)(wr + (16+col16)*36 + 16 + kgrp*4) = acc11;
    __syncthreads();

    // ---- pointwise LSTM update: thread = (batch eb, col ec) ----
    float vv[4];
#pragma unroll
    for (int g = 0; g < 4; ++g){
      int mi = eb*36 + g*8 + ec;
      vv[g] = redf[mi] + redf[1152+mi] + redf[2304+mi] + redf[3456+mi] + bias_r[g];
    }
    float fg = sigm(vv[0]), ig = sigm(vv[1]), og = sigm(vv[2]), gg = tanh_s(vv[3]);
    float cn = fg*c_st + ig*gg;
    float hn = og*tanh_s(cn);
    if (t < mylen){ c_st = cn; h_st = hn; }   // hold semantics for t >= len
    hstage[tid] = (__bf16)h_st;               // [eb][ec]
    __syncthreads();

    // ---- publish: wave0 writes 512B contiguous through to MALL, then flag ----
    if (wid == 0){
      char* hb = (layer ? h1 : h0) + (size_t)t*SLICE + lb*512;
      if (lane < 32){
        u32x4 hv = *(const u32x4*)(hstage + lane*8);
        ST16(hb + lane*16, hv);
      }
      asm volatile("s_waitcnt vmcnt(0)" ::: "memory");   // data acked at MALL
      if (lane == 0){
        int* fp = (layer ? fl1 : fl0) + lb;
        int val = t + 1;
        asm volatile("global_store_dword %0, %1, off sc0 sc1"
                     :: "v"(fp), "v"(val) : "memory");
      }
    }
    if (layer) out[((size_t)(eb*TT + t) << 10) + cgl] = h_st;  // out1[b][t][h]
  }

  // finals: out1 | c[2][B][H] | h[2][B][H]
  const size_t OFFC = (size_t)BB*TT*HH;
  out[OFFC + (layer << 15) + (eb << 10) + cgl] = c_st;
  out[OFFC + ((2 + layer) << 15) + (eb << 10) + cgl] = h_st;
}

extern "C" void kernel_launch(void* const* d_in, const int* in_sizes, int n_in,
                              void* d_out, int out_size, void* d_ws, size_t ws_size,
                              hipStream_t stream) {
  const float* x    = (const float*)d_in[0];
  const int*   lens = (const int*)d_in[1];
  const float* wih0 = (const float*)d_in[2];
  const float* whh0 = (const float*)d_in[3];
  const float* b0   = (const float*)d_in[4];
  const float* wih1 = (const float*)d_in[5];
  const float* whh1 = (const float*)d_in[6];
  const float* b1   = (const float*)d_in[7];
  float* out = (float*)d_out;
  char* ws = (char*)d_ws;

  // zero the flag words (ws is re-poisoned 0xAA before every timed call)
  (void)hipMemsetAsync(ws + FL_OFF, 0, 1024, stream);

  const int lds_bytes = 131072 + 18432 + 512;   // weights + redf + hstage = 150016
  (void)hipFuncSetAttribute((const void*)lstm2,
                            hipFuncAttributeMaxDynamicSharedMemorySize, lds_bytes);
  lstm2<<<dim3(256), dim3(256), lds_bytes, stream>>>(
      x, lens, wih0, whh0, b0, wih1, whh1, b1, out, ws);
}